// Round 7
// baseline (57.940 us; speedup 1.0000x reference)
//
#include <hip/hip_runtime.h>
#include <hip/hip_bf16.h>

typedef short short8 __attribute__((ext_vector_type(8)));
typedef float f32x4 __attribute__((ext_vector_type(4)));

#define INV_SQRT2F 0.70710678118654752440f

__device__ __forceinline__ unsigned short f2bf(float f) {
  union { float f; unsigned u; } v; v.f = f;
  unsigned u = v.u;
  unsigned r = (u + 0x7FFFu + ((u >> 16) & 1u)) >> 16;  // RNE
  return (unsigned short)r;
}

// ---------------------------------------------------------------------------
// Precompute: W'[e,:] = inverse Haar transform of W[e,:]  (since out = (W H) x),
// packed as bf16 in MFMA B-fragment layout:
//   flat bf16 index = ((nblk*8 + kk)*64 + lane)*8 + j
//   where e = nblk*16 + (lane&15), k = kk*32 + (lane>>4)*8 + j
// ---------------------------------------------------------------------------
__global__ void haar_pack(const float* __restrict__ W, unsigned short* __restrict__ Wp) {
  __shared__ float cbuf[4][256];
  __shared__ float buf0[4][256];
  __shared__ float buf1[4][256];
  const int tid = threadIdx.x;
  const int w = tid >> 6, l = tid & 63;
  const int e = blockIdx.x * 4 + w;
  const float* row = W + e * 256;
  for (int k = l; k < 256; k += 64) cbuf[w][k] = row[k];
  __syncthreads();
  if (l == 0) buf0[w][0] = cbuf[w][0];   // a = [cA_8]
  __syncthreads();
  float* A = buf0[w];
  float* Bv = buf1[w];
  int len = 1;
  // coeff layout: [cA_8(1), cD_8(1), cD_7(2), ..., cD_1(128)]; offset(cD_lev)=len
  for (int s = 0; s < 8; ++s) {
    for (int k = l; k < len; k += 64) {
      float av = A[k], dv = cbuf[w][len + k];
      Bv[2 * k]     = (av + dv) * INV_SQRT2F;   // even
      Bv[2 * k + 1] = (av - dv) * INV_SQRT2F;   // odd
    }
    __syncthreads();
    float* t = A; A = Bv; Bv = t;
    len <<= 1;
  }
  const int nblk = e >> 4, lr = e & 15;
  for (int k = l; k < 256; k += 64) {
    int kk = k >> 5, win = k & 31, lhi = win >> 3, j = win & 7;
    int lane = lhi * 16 + lr;
    Wp[(((nblk * 8 + kk) * 64 + lane) << 3) + j] = f2bf(A[k]);
  }
}

// ---------------------------------------------------------------------------
// Persistent-block streaming GEMM: out[m,e] = sum_k x[m,k] W'[e,k] + b[e]
// - __launch_bounds__(512,1): 256-VGPR budget so Bf[8][4] (128 VGPR) truly
//   lives in registers (R6's (512,2) capped at 128 -> scratch spill).
// - Depth-2 register prefetch (pfA/pfB, static names, unroll-by-2): loads
//   for tile t+2 issued one full iteration before their ds_write.
// - lgkm-only barriers: stores NEVER drained in-loop (no vmcnt(0)); the
//   compiler emits counted vmcnt waits for the pf dependency only.
// - 8 waves (2 wm x 4 wn), wave tile 16x64; 16 tiles of 32 rows; grid 256.
// - A tile XOR-swizzled: byte ^= (row&7)<<4 (2-way-max b128 reads = free).
// ---------------------------------------------------------------------------
#define NTILES 16
#define BM 32

#define BARRIER_LGKM() do { \
    __builtin_amdgcn_sched_barrier(0); \
    asm volatile("s_waitcnt lgkmcnt(0)" ::: "memory"); \
    __builtin_amdgcn_s_barrier(); \
    __builtin_amdgcn_sched_barrier(0); \
  } while (0)

__global__ __launch_bounds__(512, 1) void wemb_gemm(
    const float* __restrict__ x, const unsigned short* __restrict__ Wp,
    const float* __restrict__ bias, float* __restrict__ out) {
  __shared__ char al[2][16384];
  const int tid = threadIdx.x;
  const int w = tid >> 6, lane = tid & 63;
  const int wm = w >> 2, wn = w & 3;      // 2 x 4 wave grid
  const int lr = lane & 15, lhi = lane >> 4;

  // ---- B fragments -> registers, loaded once, pinned ----
  short8 Bf[8][4];   // [kk][n]
#pragma unroll
  for (int kk = 0; kk < 8; ++kk)
#pragma unroll
    for (int n = 0; n < 4; ++n)
      Bf[kk][n] = *(const short8*)(Wp + ((((wn * 4 + n) * 8 + kk) * 64 + lane) << 3));
#pragma unroll
  for (int kk = 0; kk < 8; ++kk)
#pragma unroll
    for (int n = 0; n < 4; ++n)
      asm volatile("" : "+v"(Bf[kk][n]));   // pin: forbids re-load/sink

  float bv[4];
#pragma unroll
  for (int n = 0; n < 4; ++n) bv[n] = bias[wn * 64 + n * 16 + lr];

  const long tile0 = (long)blockIdx.x * NTILES;
  float4 pfA[4], pfB[4];

  // ---- prologue: stage tile 0 -> al[0]; issue tile-1 loads into pfA ----
  {
    const float4* s0 = (const float4*)(x + tile0 * (BM * 256));
    float4 t0[4];
#pragma unroll
    for (int i = 0; i < 4; ++i) t0[i] = s0[i * 512 + tid];
    const float4* s1 = (const float4*)(x + (tile0 + 1) * (BM * 256));
#pragma unroll
    for (int i = 0; i < 4; ++i) pfA[i] = s1[i * 512 + tid];
#pragma unroll
    for (int i = 0; i < 4; ++i) {
      int f = i * 512 + tid;
      int row = f >> 6, colb = (f & 63) * 8;
      ushort4 p;
      p.x = __bfloat16_as_ushort(__float2bfloat16(t0[i].x));
      p.y = __bfloat16_as_ushort(__float2bfloat16(t0[i].y));
      p.z = __bfloat16_as_ushort(__float2bfloat16(t0[i].z));
      p.w = __bfloat16_as_ushort(__float2bfloat16(t0[i].w));
      *(ushort4*)(al[0] + row * 512 + (colb ^ ((row & 7) << 4))) = p;
    }
  }
  BARRIER_LGKM();

  // ---- main loop: unrolled by 2 so pfA/pfB and cur/nxt are static ----
#define STEP(IT, CUR, NXT, PFU, PFL)                                          \
  {                                                                           \
    const long tt = tile0 + (IT);                                             \
    if ((IT) + 2 < NTILES) {                                                  \
      const float4* src = (const float4*)(x + (tt + 2) * (BM * 256));         \
      _Pragma("unroll")                                                       \
      for (int i = 0; i < 4; ++i) PFL[i] = src[i * 512 + tid];                \
    }                                                                         \
    f32x4 acc[4];                                                             \
    _Pragma("unroll")                                                         \
    for (int n = 0; n < 4; ++n) acc[n] = (f32x4){0.f, 0.f, 0.f, 0.f};         \
    _Pragma("unroll")                                                         \
    for (int kk = 0; kk < 8; ++kk) {                                          \
      const int arow = wm * 16 + lr;                                          \
      const int colb = (kk * 32 + lhi * 8) * 2;                               \
      short8 a = *(const short8*)((CUR) + arow * 512 +                        \
                                  (colb ^ ((arow & 7) << 4)));                \
      _Pragma("unroll")                                                       \
      for (int n = 0; n < 4; ++n)                                             \
        acc[n] = __builtin_amdgcn_mfma_f32_16x16x32_bf16(a, Bf[kk][n],        \
                                                         acc[n], 0, 0, 0);    \
    }                                                                         \
    {                                                                         \
      float* orow = out + (tt * BM + wm * 16 + lhi * 4) * 256;                \
      _Pragma("unroll")                                                       \
      for (int n = 0; n < 4; ++n) {                                           \
        const int e = wn * 64 + n * 16 + lr;                                  \
        _Pragma("unroll")                                                     \
        for (int r = 0; r < 4; ++r) orow[r * 256 + e] = acc[n][r] + bv[n];    \
      }                                                                       \
    }                                                                         \
    if ((IT) + 1 < NTILES) {                                                  \
      _Pragma("unroll")                                                       \
      for (int i = 0; i < 4; ++i) {                                           \
        int f = i * 512 + tid;                                                \
        int row = f >> 6, colb = (f & 63) * 8;                                \
        ushort4 p;                                                            \
        p.x = __bfloat16_as_ushort(__float2bfloat16(PFU[i].x));               \
        p.y = __bfloat16_as_ushort(__float2bfloat16(PFU[i].y));               \
        p.z = __bfloat16_as_ushort(__float2bfloat16(PFU[i].z));               \
        p.w = __bfloat16_as_ushort(__float2bfloat16(PFU[i].w));               \
        *(ushort4*)((NXT) + row * 512 + (colb ^ ((row & 7) << 4))) = p;       \
      }                                                                       \
      BARRIER_LGKM();                                                         \
    }                                                                         \
  }

#pragma unroll 1
  for (int ip = 0; ip < NTILES / 2; ++ip) {
    const int it0 = ip * 2;
    STEP(it0,     al[0], al[1], pfA, pfB);
    STEP(it0 + 1, al[1], al[0], pfB, pfA);
  }
#undef STEP
}

extern "C" void kernel_launch(void* const* d_in, const int* in_sizes, int n_in,
                              void* d_out, int out_size, void* d_ws, size_t ws_size,
                              hipStream_t stream) {
  const float* x = (const float*)d_in[0];     // (16, 8192, 256) fp32
  const float* W = (const float*)d_in[1];     // (256, 256) fp32
  const float* b = (const float*)d_in[2];     // (256,) fp32
  float* out = (float*)d_out;                 // (16, 8192, 256) fp32
  unsigned short* Wp = (unsigned short*)d_ws; // 256*256 bf16 = 128 KB

  haar_pack<<<64, 256, 0, stream>>>(W, Wp);

  const int grid = (out_size / 256) / (BM * NTILES);  // 131072 / 512 = 256
  wemb_gemm<<<grid, 512, 0, stream>>>(x, Wp, b, out);
}